// Round 12
// baseline (3690.956 us; speedup 1.0000x reference)
//
#include <hip/hip_runtime.h>

#define T_STEPS 19
#define NBATCH  65536
#define RNN     256
#define EMB     128
#define KDIM    384   // RNN + EMB
#define ROWB    768   // KDIM * 2 bytes (LDS row stride)
// swizzle bits 4-5 only: commutes with +kk*64 (bits>=6) so ds_read imm offsets work.
// a-frag b128 reads stay conflict-free: start-slot = f(csub&3 ^ kq) covers all 8.
#define SWZ(row) (((row) & 3) << 4)

typedef __bf16 bf16x8 __attribute__((ext_vector_type(8)));
typedef float  f32x4  __attribute__((ext_vector_type(4)));

#define BLOCK_SYNC() asm volatile("s_waitcnt lgkmcnt(0)\n\ts_barrier" ::: "memory")

__device__ __forceinline__ unsigned short f2bf(float f) {
    unsigned u = __float_as_uint(f);
    u += 0x7fffu + ((u >> 16) & 1u);
    return (unsigned short)(u >> 16);
}
__device__ __forceinline__ float bf2f(unsigned short u) {
    return __uint_as_float(((unsigned)u) << 16);
}
__device__ __forceinline__ float sigm_(float x) {
    float e = __expf(-x);
    return __builtin_amdgcn_rcpf(1.0f + e);
}
__device__ __forceinline__ float tanh_(float x) {
    float e = __expf(2.0f * x);
    return 1.0f - 2.0f * __builtin_amdgcn_rcpf(e + 1.0f);
}

// ---- prep: Wcat fragments for 16x16x32 MFMA, wave-private slices (round-7 layout) ----
// uint4 idx = ((w*12 + kk)*4 + g)*64 + l
//   j = g*256 + w*16 + (l&15) ; k = kk*32 + (l>>4)*8 + e
__global__ void prep_wcat(const float* __restrict__ Whh, const float* __restrict__ Wih,
                          unsigned short* __restrict__ dst) {
    int tid = blockIdx.x * 256 + threadIdx.x;   // 49152 total
    int l   = tid & 63;
    int p   = tid >> 6;
    int g   = p & 3;
    int kkw = p >> 2;
    int kk  = kkw % 12;
    int w   = kkw / 12;
    int j   = g * 256 + w * 16 + (l & 15);
    int kb  = kk * 32 + (l >> 4) * 8;
    unsigned short v[8];
#pragma unroll
    for (int e = 0; e < 8; ++e) {
        int k = kb + e;
        float f = (k < 256) ? Whh[j * 256 + k] : Wih[j * 128 + (k - 256)];
        v[e] = f2bf(f);
    }
    uint4 pk;
    pk.x = (unsigned)v[0] | ((unsigned)v[1] << 16);
    pk.y = (unsigned)v[2] | ((unsigned)v[3] << 16);
    pk.z = (unsigned)v[4] | ((unsigned)v[5] << 16);
    pk.w = (unsigned)v[6] | ((unsigned)v[7] << 16);
    ((uint4*)dst)[tid] = pk;
}

// ---- prep: Wout fragments for 16x16x32 (16-col tile, cols 5..15 zero) ----
__global__ void prep_wout(const float* __restrict__ Wout, unsigned short* __restrict__ dst) {
    int tid = blockIdx.x * 256 + threadIdx.x;   // 512 total
    if (tid >= 512) return;
    int l  = tid & 63;
    int kk = tid >> 6;
    int q  = l & 15;
    int kb = kk * 32 + (l >> 4) * 8;
    unsigned short v[8];
#pragma unroll
    for (int e = 0; e < 8; ++e) {
        float f = (q < 5) ? Wout[q * 256 + kb + e] : 0.0f;
        v[e] = f2bf(f);
    }
    uint4 pk;
    pk.x = (unsigned)v[0] | ((unsigned)v[1] << 16);
    pk.y = (unsigned)v[2] | ((unsigned)v[3] << 16);
    pk.z = (unsigned)v[4] | ((unsigned)v[5] << 16);
    pk.w = (unsigned)v[6] | ((unsigned)v[7] << 16);
    ((uint4*)dst)[tid] = pk;
}

__global__ void prep_bias(const float* __restrict__ bih, const float* __restrict__ bhh,
                          float* __restrict__ dst) {
    int tid = blockIdx.x * 256 + threadIdx.x;
    if (tid < 1024) dst[tid] = bih[tid] + bhh[tid];
}

// ---- main persistent-over-T kernel: 1 block = 64 samples, 16 waves, 4 waves/SIMD ----
// Round-7 schedule (synchronized sweeps -> L2 locality) with a fully-unrolled,
// compile-time-addressed B loop (imm ds_read offsets, static refill indices)
// and x/mask prefetched one step ahead.
__global__ __launch_bounds__(1024, 4)
void lstm_main(const float* __restrict__ x_in, const float* __restrict__ h_in,
               const float* __restrict__ c_in, const int* __restrict__ mask,
               const float* __restrict__ W_emb, const float* __restrict__ b_emb,
               const float* __restrict__ b_out,
               const unsigned short* __restrict__ wcat_fr,
               const unsigned short* __restrict__ wout_fr,
               const float* __restrict__ bias_g,
               float* __restrict__ out) {
    __shared__ unsigned short A_lds[64 * KDIM];   // 48 KB, SWZ(bits 4-5)
    __shared__ float c_lds[64 * RNN];             // 64 KB fp32 c state
    __shared__ float we_lds[384];                 // W_emb(256) + b_emb(128)

    const int tid  = threadIdx.x;
    const int lane = tid & 63;
    const int w    = tid >> 6;         // wave 0..15 = unit-block
    const int base = blockIdx.x * 64;
    const int csub = lane & 15;
    const int kq   = lane >> 4;        // 0..3
    const int unit = w * 16 + csub;

    // init: h0 -> A_lds (bf16), c0 -> c_lds (fp32)
#pragma unroll
    for (int m = 0; m < 4; ++m)
#pragma unroll
        for (int r = 0; r < 4; ++r) {
            int row = m * 16 + kq * 4 + r;
            float hv = h_in[(size_t)(base + row) * RNN + unit];
            c_lds[row * RNN + unit] = c_in[(size_t)(base + row) * RNN + unit];
            int byte = (row * ROWB + unit * 2) ^ SWZ(row);
            A_lds[byte >> 1] = f2bf(hv);
        }
    if (tid < 384) we_lds[tid] = (tid < 256) ? W_emb[tid] : b_emb[tid - 256];

    float bias4[4];
#pragma unroll
    for (int g = 0; g < 4; ++g) bias4[g] = bias_g[g * 256 + unit];
    const float bo = (csub < 5) ? b_out[csub] : 0.0f;

    const uint4* wfp = (const uint4*)wcat_fr + (size_t)w * (12 * 4 * 64) + lane;
    const uint4* wop = (const uint4*)wout_fr + lane;

    // per-m LDS byte base for a-frag reads (kk term added as compile-time imm)
    int a_base[4];
#pragma unroll
    for (int m = 0; m < 4; ++m) {
        int row = m * 16 + csub;
        a_base[m] = (row * ROWB + kq * 16) ^ SWZ(row);
    }

    // persistent depth-2 weight pipeline (regs), wraps across steps
    bf16x8 bA[4], bB[4];
#pragma unroll
    for (int g = 0; g < 4; ++g) bA[g] = *(const bf16x8*)(wfp + (0 * 4 + g) * 64);
#pragma unroll
    for (int g = 0; g < 4; ++g) bB[g] = *(const bf16x8*)(wfp + (1 * 4 + g) * 64);

    // x/mask prefetch for t=0
    const int xrow = tid >> 4, xjc = (tid & 15) * 8;
    float xc0, xc1;
    {
        const float* xp = x_in + ((size_t)base + xrow) * 2;
        xc0 = xp[0]; xc1 = xp[1];
    }
    int mvc = mask[base + lane];

    BLOCK_SYNC();  // init LDS (h, c, we_lds) visible

    for (int t = 0; t < T_STEPS; ++t) {
        unsigned long long mbits = __ballot(mvc != 0);

        // ---- Phase A: e(t) = relu(x @ W_emb + b_emb) from prefetched x ----
        {
            unsigned pk[4];
#pragma unroll
            for (int e = 0; e < 8; e += 2) {
                int j = xjc + e;
                float e0 = fmaxf(fmaf(xc0, we_lds[j],     fmaf(xc1, we_lds[128 + j],     we_lds[256 + j])),     0.0f);
                float e1 = fmaxf(fmaf(xc0, we_lds[j + 1], fmaf(xc1, we_lds[128 + j + 1], we_lds[256 + j + 1])), 0.0f);
                pk[e >> 1] = (unsigned)f2bf(e0) | ((unsigned)f2bf(e1) << 16);
            }
            int byte = (xrow * ROWB + 512 + 2 * xjc) ^ SWZ(xrow);
            *(uint4*)((char*)A_lds + byte) = make_uint4(pk[0], pk[1], pk[2], pk[3]);
        }
        // prefetch x/mask for t+1 (lands during B+C)
        {
            int tn = (t + 1 < T_STEPS) ? t + 1 : t;
            const float* xp = x_in + ((size_t)tn * NBATCH + base + xrow) * 2;
            xc0 = xp[0]; xc1 = xp[1];
            mvc = mask[(size_t)tn * NBATCH + base + lane];
        }
        BLOCK_SYNC();  // bar1: A_lds ready

        // ---- Phase B: fully unrolled 12 K=32 slices, compile-time addressing ----
        f32x4 acc[4][4];
#pragma unroll
        for (int m = 0; m < 4; ++m)
#pragma unroll
            for (int g = 0; g < 4; ++g) {
                f32x4 z = {bias4[g], bias4[g], bias4[g], bias4[g]};
                acc[m][g] = z;
            }
#pragma unroll
        for (int kp = 0; kp < 6; ++kp) {
            const int kk0 = kp * 2;
            // even half: consume bA (slice kk0), refill with (kk0+2)%12
#pragma unroll
            for (int m = 0; m < 4; ++m) {
                bf16x8 a = *(const bf16x8*)((const char*)A_lds + a_base[m] + kk0 * 64);
                acc[m][0] = __builtin_amdgcn_mfma_f32_16x16x32_bf16(a, bA[0], acc[m][0], 0, 0, 0);
                acc[m][1] = __builtin_amdgcn_mfma_f32_16x16x32_bf16(a, bA[1], acc[m][1], 0, 0, 0);
                acc[m][2] = __builtin_amdgcn_mfma_f32_16x16x32_bf16(a, bA[2], acc[m][2], 0, 0, 0);
                acc[m][3] = __builtin_amdgcn_mfma_f32_16x16x32_bf16(a, bA[3], acc[m][3], 0, 0, 0);
            }
            {
                const int knA = (kk0 + 2) % 12;   // compile-time
#pragma unroll
                for (int g = 0; g < 4; ++g)
                    bA[g] = *(const bf16x8*)(wfp + (knA * 4 + g) * 64);
            }
            // odd half: consume bB (slice kk0+1), refill with (kk0+3)%12
#pragma unroll
            for (int m = 0; m < 4; ++m) {
                bf16x8 a = *(const bf16x8*)((const char*)A_lds + a_base[m] + (kk0 + 1) * 64);
                acc[m][0] = __builtin_amdgcn_mfma_f32_16x16x32_bf16(a, bB[0], acc[m][0], 0, 0, 0);
                acc[m][1] = __builtin_amdgcn_mfma_f32_16x16x32_bf16(a, bB[1], acc[m][1], 0, 0, 0);
                acc[m][2] = __builtin_amdgcn_mfma_f32_16x16x32_bf16(a, bB[2], acc[m][2], 0, 0, 0);
                acc[m][3] = __builtin_amdgcn_mfma_f32_16x16x32_bf16(a, bB[3], acc[m][3], 0, 0, 0);
            }
            {
                const int knB = (kk0 + 3) % 12;   // compile-time
#pragma unroll
                for (int g = 0; g < 4; ++g)
                    bB[g] = *(const bf16x8*)(wfp + (knB * 4 + g) * 64);
            }
        }
        BLOCK_SYNC();  // bar2: all A_lds reads done before h overwrite

        // ---- Phase C: elementwise update; c in LDS, h (bf16) back to A_lds ----
#pragma unroll
        for (int m = 0; m < 4; ++m)
#pragma unroll
            for (int r = 0; r < 4; ++r) {
                int row = m * 16 + kq * 4 + r;
                float cv = c_lds[row * RNN + unit];
                float iv = sigm_(acc[m][0][r]);
                float fv = sigm_(acc[m][1][r]);
                float gv = tanh_(acc[m][2][r]);
                float ov = sigm_(acc[m][3][r]);
                float cn = fmaf(fv, cv, iv * gv);
                float hn = ov * tanh_(cn);
                int msk = (int)((mbits >> row) & 1ull);
                if (msk) {
                    c_lds[row * RNN + unit] = cn;
                    int byte = (row * ROWB + unit * 2) ^ SWZ(row);
                    A_lds[byte >> 1] = f2bf(hn);
                }
            }
        BLOCK_SYNC();  // bar3: new h visible

        // ---- Phase D: out = h @ Wout^T + b_out (waves 0..3), overlaps next Phase A ----
        if (w < 4) {
            f32x4 oacc = {bo, bo, bo, bo};
#pragma unroll
            for (int kk = 0; kk < 8; ++kk) {
                int row = w * 16 + csub;
                int byte = ((row * ROWB + kq * 16) ^ SWZ(row)) + kk * 64;
                bf16x8 a  = *(const bf16x8*)((const char*)A_lds + byte);
                bf16x8 bw = *(const bf16x8*)(wop + kk * 64);
                oacc = __builtin_amdgcn_mfma_f32_16x16x32_bf16(a, bw, oacc, 0, 0, 0);
            }
            if (csub < 5) {
#pragma unroll
                for (int r = 0; r < 4; ++r) {
                    int row = w * 16 + kq * 4 + r;
                    int msk = (int)((mbits >> row) & 1ull);
                    out[((size_t)t * NBATCH + base + row) * 5 + csub] = msk ? oacc[r] : 0.0f;
                }
            }
        }
        // no barrier: D reads h-region (k<256); next A writes e-region (k>=256) — disjoint.
        // C(t+1) writes are behind bar1+bar2.
    }

    // ---- final states: h from A_lds (bf16), c from c_lds (fp32) ----
    float* hout = out + (size_t)T_STEPS * NBATCH * 5;
    float* cout = hout + (size_t)NBATCH * RNN;
#pragma unroll
    for (int m = 0; m < 4; ++m)
#pragma unroll
        for (int r = 0; r < 4; ++r) {
            int row = m * 16 + kq * 4 + r;
            int byte = (row * ROWB + unit * 2) ^ SWZ(row);
            hout[(size_t)(base + row) * RNN + unit] = bf2f(A_lds[byte >> 1]);
            cout[(size_t)(base + row) * RNN + unit] = c_lds[row * RNN + unit];
        }
}

extern "C" void kernel_launch(void* const* d_in, const int* in_sizes, int n_in,
                              void* d_out, int out_size, void* d_ws, size_t ws_size,
                              hipStream_t stream) {
    (void)in_sizes; (void)n_in; (void)out_size; (void)ws_size;
    const float* x_in = (const float*)d_in[0];
    const float* h0   = (const float*)d_in[1];
    const float* c0   = (const float*)d_in[2];
    const int*   mk   = (const int*)d_in[3];
    const float* Wemb = (const float*)d_in[4];
    const float* bemb = (const float*)d_in[5];
    const float* Wih  = (const float*)d_in[6];
    const float* bih  = (const float*)d_in[7];
    const float* Whh  = (const float*)d_in[8];
    const float* bhh  = (const float*)d_in[9];
    const float* Wout = (const float*)d_in[10];
    const float* bout = (const float*)d_in[11];

    unsigned short* wcat = (unsigned short*)d_ws;        // 49152 uint4 = 768 KB
    unsigned short* wouf = wcat + 393216;                // 512 uint4 = 8 KB
    float*          bsg  = (float*)(wouf + 4096);        // 1024 f32

    prep_wcat<<<192, 256, 0, stream>>>(Whh, Wih, wcat);
    prep_wout<<<2, 256, 0, stream>>>(Wout, wouf);
    prep_bias<<<4, 256, 0, stream>>>(bih, bhh, bsg);

    float* outp = (float*)d_out;
    lstm_main<<<1024, 1024, 0, stream>>>(x_in, h0, c0, mk, Wemb, bemb, bout,
                                         wcat, wouf, bsg, outp);
}

// Round 13
// 3602.192 us; speedup vs baseline: 1.0246x; 1.0246x over previous
//
#include <hip/hip_runtime.h>

#define T_STEPS 19
#define NBATCH  65536
#define RNN     256
#define EMB     128
#define KDIM    384   // RNN + EMB
#define SLC     5120  // bytes per kk-slice: 64 rows * 80 B (padded from 64)
#define RSTR    80    // padded row stride within a slice

typedef __bf16 bf16x8 __attribute__((ext_vector_type(8)));
typedef float  f32x4  __attribute__((ext_vector_type(4)));

#define BLOCK_SYNC() asm volatile("s_waitcnt lgkmcnt(0)\n\ts_barrier" ::: "memory")

__device__ __forceinline__ unsigned short f2bf(float f) {
    unsigned u = __float_as_uint(f);
    u += 0x7fffu + ((u >> 16) & 1u);
    return (unsigned short)(u >> 16);
}
__device__ __forceinline__ float bf2f(unsigned short u) {
    return __uint_as_float(((unsigned)u) << 16);
}
__device__ __forceinline__ float sigm_(float x) {
    float e = __expf(-x);
    return __builtin_amdgcn_rcpf(1.0f + e);
}
__device__ __forceinline__ float tanh_(float x) {
    float e = __expf(2.0f * x);
    return 1.0f - 2.0f * __builtin_amdgcn_rcpf(e + 1.0f);
}
// element-k (0..383) byte offset in the kk-major padded A tile
__device__ __forceinline__ int aoff(int row, int k) {
    return (k >> 5) * SLC + row * RSTR + (k & 31) * 2;
}

// ---- prep: Wcat fragments for 16x16x32 MFMA, wave-private slices (r7 layout) ----
// uint4 idx = ((w*12 + kk)*4 + g)*64 + l
//   j = g*256 + w*16 + (l&15) ; k = kk*32 + (l>>4)*8 + e
__global__ void prep_wcat(const float* __restrict__ Whh, const float* __restrict__ Wih,
                          unsigned short* __restrict__ dst) {
    int tid = blockIdx.x * 256 + threadIdx.x;   // 49152 total
    int l   = tid & 63;
    int p   = tid >> 6;
    int g   = p & 3;
    int kkw = p >> 2;
    int kk  = kkw % 12;
    int w   = kkw / 12;
    int j   = g * 256 + w * 16 + (l & 15);
    int kb  = kk * 32 + (l >> 4) * 8;
    unsigned short v[8];
#pragma unroll
    for (int e = 0; e < 8; ++e) {
        int k = kb + e;
        float f = (k < 256) ? Whh[j * 256 + k] : Wih[j * 128 + (k - 256)];
        v[e] = f2bf(f);
    }
    uint4 pk;
    pk.x = (unsigned)v[0] | ((unsigned)v[1] << 16);
    pk.y = (unsigned)v[2] | ((unsigned)v[3] << 16);
    pk.z = (unsigned)v[4] | ((unsigned)v[5] << 16);
    pk.w = (unsigned)v[6] | ((unsigned)v[7] << 16);
    ((uint4*)dst)[tid] = pk;
}

// ---- prep: Wout fragments for 16x16x32 (16-col tile, cols 5..15 zero) ----
__global__ void prep_wout(const float* __restrict__ Wout, unsigned short* __restrict__ dst) {
    int tid = blockIdx.x * 256 + threadIdx.x;   // 512 total
    if (tid >= 512) return;
    int l  = tid & 63;
    int kk = tid >> 6;
    int q  = l & 15;
    int kb = kk * 32 + (l >> 4) * 8;
    unsigned short v[8];
#pragma unroll
    for (int e = 0; e < 8; ++e) {
        float f = (q < 5) ? Wout[q * 256 + kb + e] : 0.0f;
        v[e] = f2bf(f);
    }
    uint4 pk;
    pk.x = (unsigned)v[0] | ((unsigned)v[1] << 16);
    pk.y = (unsigned)v[2] | ((unsigned)v[3] << 16);
    pk.z = (unsigned)v[4] | ((unsigned)v[5] << 16);
    pk.w = (unsigned)v[6] | ((unsigned)v[7] << 16);
    ((uint4*)dst)[tid] = pk;
}

__global__ void prep_bias(const float* __restrict__ bih, const float* __restrict__ bhh,
                          float* __restrict__ dst) {
    int tid = blockIdx.x * 256 + threadIdx.x;
    if (tid < 1024) dst[tid] = bih[tid] + bhh[tid];
}

// ---- main persistent-over-T kernel: 1 block = 64 samples, 16 waves, 4 waves/SIMD ----
// r7 schedule; A tile in kk-major padded layout (imm ds_read offsets, no XOR);
// fully-unrolled B loop with static refill indices; x/mask prefetch.
__global__ __launch_bounds__(1024, 4)
void lstm_main(const float* __restrict__ x_in, const float* __restrict__ h_in,
               const float* __restrict__ c_in, const int* __restrict__ mask,
               const float* __restrict__ W_emb, const float* __restrict__ b_emb,
               const float* __restrict__ b_out,
               const unsigned short* __restrict__ wcat_fr,
               const unsigned short* __restrict__ wout_fr,
               const float* __restrict__ bias_g,
               float* __restrict__ out) {
    __shared__ char  A_lds[12 * SLC];        // 60 KB: [kk][row][32 elems] padded
    __shared__ float c_lds[64 * 257];        // 64.3 KB: fp32 c, stride 257 (no 4-way)
    __shared__ float we_lds[384];            // W_emb(256) + b_emb(128)

    const int tid  = threadIdx.x;
    const int lane = tid & 63;
    const int w    = tid >> 6;         // wave 0..15 = unit-block
    const int base = blockIdx.x * 64;
    const int csub = lane & 15;
    const int kq   = lane >> 4;        // 0..3
    const int unit = w * 16 + csub;

    // init: h0 -> A_lds (bf16), c0 -> c_lds (fp32)
#pragma unroll
    for (int m = 0; m < 4; ++m)
#pragma unroll
        for (int r = 0; r < 4; ++r) {
            int row = m * 16 + kq * 4 + r;
            float hv = h_in[(size_t)(base + row) * RNN + unit];
            c_lds[row * 257 + unit] = c_in[(size_t)(base + row) * RNN + unit];
            *(unsigned short*)(A_lds + aoff(row, unit)) = f2bf(hv);
        }
    if (tid < 384) we_lds[tid] = (tid < 256) ? W_emb[tid] : b_emb[tid - 256];

    float bias4[4];
#pragma unroll
    for (int g = 0; g < 4; ++g) bias4[g] = bias_g[g * 256 + unit];
    const float bo = (csub < 5) ? b_out[csub] : 0.0f;

    const uint4* wfp = (const uint4*)wcat_fr + (size_t)w * (12 * 4 * 64) + lane;
    const uint4* wop = (const uint4*)wout_fr + lane;

    // per-m LDS byte base for a-frag reads; kk term is a compile-time imm offset
    int a_base[4];
#pragma unroll
    for (int m = 0; m < 4; ++m)
        a_base[m] = (m * 16 + csub) * RSTR + kq * 16;

    // persistent depth-2 weight pipeline (regs), wraps across steps
    bf16x8 bA[4], bB[4];
#pragma unroll
    for (int g = 0; g < 4; ++g) bA[g] = *(const bf16x8*)(wfp + (0 * 4 + g) * 64);
#pragma unroll
    for (int g = 0; g < 4; ++g) bB[g] = *(const bf16x8*)(wfp + (1 * 4 + g) * 64);

    // x/mask prefetch for t=0
    const int xrow = tid >> 4, xjc = (tid & 15) * 8;
    float xc0, xc1;
    {
        const float* xp = x_in + ((size_t)base + xrow) * 2;
        xc0 = xp[0]; xc1 = xp[1];
    }
    int mvc = mask[base + lane];

    BLOCK_SYNC();  // init LDS (h, c, we_lds) visible

    for (int t = 0; t < T_STEPS; ++t) {
        unsigned long long mbits = __ballot(mvc != 0);

        // ---- Phase A: e(t) = relu(x @ W_emb + b_emb) from prefetched x ----
        {
            unsigned pk[4];
#pragma unroll
            for (int e = 0; e < 8; e += 2) {
                int j = xjc + e;
                float e0 = fmaxf(fmaf(xc0, we_lds[j],     fmaf(xc1, we_lds[128 + j],     we_lds[256 + j])),     0.0f);
                float e1 = fmaxf(fmaf(xc0, we_lds[j + 1], fmaf(xc1, we_lds[128 + j + 1], we_lds[256 + j + 1])), 0.0f);
                pk[e >> 1] = (unsigned)f2bf(e0) | ((unsigned)f2bf(e1) << 16);
            }
            *(uint4*)(A_lds + aoff(xrow, 256 + xjc)) = make_uint4(pk[0], pk[1], pk[2], pk[3]);
        }
        // prefetch x/mask for t+1 (lands during B+C)
        {
            int tn = (t + 1 < T_STEPS) ? t + 1 : t;
            const float* xp = x_in + ((size_t)tn * NBATCH + base + xrow) * 2;
            xc0 = xp[0]; xc1 = xp[1];
            mvc = mask[(size_t)tn * NBATCH + base + lane];
        }
        BLOCK_SYNC();  // bar1: A_lds ready

        // ---- Phase B: fully unrolled 12 K=32 slices, imm-offset ds_reads ----
        f32x4 acc[4][4];
#pragma unroll
        for (int m = 0; m < 4; ++m)
#pragma unroll
            for (int g = 0; g < 4; ++g) {
                f32x4 z = {bias4[g], bias4[g], bias4[g], bias4[g]};
                acc[m][g] = z;
            }
#pragma unroll
        for (int kp = 0; kp < 6; ++kp) {
            const int kk0 = kp * 2;
            // even half: consume bA (slice kk0), refill with (kk0+2)%12
#pragma unroll
            for (int m = 0; m < 4; ++m) {
                bf16x8 a = *(const bf16x8*)(A_lds + kk0 * SLC + a_base[m]);
                acc[m][0] = __builtin_amdgcn_mfma_f32_16x16x32_bf16(a, bA[0], acc[m][0], 0, 0, 0);
                acc[m][1] = __builtin_amdgcn_mfma_f32_16x16x32_bf16(a, bA[1], acc[m][1], 0, 0, 0);
                acc[m][2] = __builtin_amdgcn_mfma_f32_16x16x32_bf16(a, bA[2], acc[m][2], 0, 0, 0);
                acc[m][3] = __builtin_amdgcn_mfma_f32_16x16x32_bf16(a, bA[3], acc[m][3], 0, 0, 0);
            }
            {
                const int knA = (kk0 + 2) % 12;   // compile-time
#pragma unroll
                for (int g = 0; g < 4; ++g)
                    bA[g] = *(const bf16x8*)(wfp + (knA * 4 + g) * 64);
            }
            // odd half: consume bB (slice kk0+1), refill with (kk0+3)%12
#pragma unroll
            for (int m = 0; m < 4; ++m) {
                bf16x8 a = *(const bf16x8*)(A_lds + (kk0 + 1) * SLC + a_base[m]);
                acc[m][0] = __builtin_amdgcn_mfma_f32_16x16x32_bf16(a, bB[0], acc[m][0], 0, 0, 0);
                acc[m][1] = __builtin_amdgcn_mfma_f32_16x16x32_bf16(a, bB[1], acc[m][1], 0, 0, 0);
                acc[m][2] = __builtin_amdgcn_mfma_f32_16x16x32_bf16(a, bB[2], acc[m][2], 0, 0, 0);
                acc[m][3] = __builtin_amdgcn_mfma_f32_16x16x32_bf16(a, bB[3], acc[m][3], 0, 0, 0);
            }
            {
                const int knB = (kk0 + 3) % 12;   // compile-time
#pragma unroll
                for (int g = 0; g < 4; ++g)
                    bB[g] = *(const bf16x8*)(wfp + (knB * 4 + g) * 64);
            }
        }
        BLOCK_SYNC();  // bar2: all A_lds reads done before h overwrite

        // ---- Phase C: elementwise update; c in LDS(257-stride), h (bf16) to A_lds ----
#pragma unroll
        for (int m = 0; m < 4; ++m)
#pragma unroll
            for (int r = 0; r < 4; ++r) {
                int row = m * 16 + kq * 4 + r;
                float cv = c_lds[row * 257 + unit];
                float iv = sigm_(acc[m][0][r]);
                float fv = sigm_(acc[m][1][r]);
                float gv = tanh_(acc[m][2][r]);
                float ov = sigm_(acc[m][3][r]);
                float cn = fmaf(fv, cv, iv * gv);
                float hn = ov * tanh_(cn);
                int msk = (int)((mbits >> row) & 1ull);
                if (msk) {
                    c_lds[row * 257 + unit] = cn;
                    *(unsigned short*)(A_lds + aoff(row, unit)) = f2bf(hn);
                }
            }
        BLOCK_SYNC();  // bar3: new h visible

        // ---- Phase D: out = h @ Wout^T + b_out (waves 0..3), overlaps next Phase A ----
        if (w < 4) {
            f32x4 oacc = {bo, bo, bo, bo};
            int d_base = (w * 16 + csub) * RSTR + kq * 16;
#pragma unroll
            for (int kk = 0; kk < 8; ++kk) {
                bf16x8 a  = *(const bf16x8*)(A_lds + kk * SLC + d_base);
                bf16x8 bw = *(const bf16x8*)(wop + kk * 64);
                oacc = __builtin_amdgcn_mfma_f32_16x16x32_bf16(a, bw, oacc, 0, 0, 0);
            }
            if (csub < 5) {
#pragma unroll
                for (int r = 0; r < 4; ++r) {
                    int row = w * 16 + kq * 4 + r;
                    int msk = (int)((mbits >> row) & 1ull);
                    out[((size_t)t * NBATCH + base + row) * 5 + csub] = msk ? oacc[r] : 0.0f;
                }
            }
        }
        // no barrier: D reads h-slices (kk<8); next A writes e-slices (kk>=8) — disjoint.
        // C(t+1) writes are behind bar1+bar2.
    }

    // ---- final states: h from A_lds (bf16), c from c_lds (fp32) ----
    float* hout = out + (size_t)T_STEPS * NBATCH * 5;
    float* cout = hout + (size_t)NBATCH * RNN;
#pragma unroll
    for (int m = 0; m < 4; ++m)
#pragma unroll
        for (int r = 0; r < 4; ++r) {
            int row = m * 16 + kq * 4 + r;
            hout[(size_t)(base + row) * RNN + unit] =
                bf2f(*(const unsigned short*)(A_lds + aoff(row, unit)));
            cout[(size_t)(base + row) * RNN + unit] = c_lds[row * 257 + unit];
        }
}

extern "C" void kernel_launch(void* const* d_in, const int* in_sizes, int n_in,
                              void* d_out, int out_size, void* d_ws, size_t ws_size,
                              hipStream_t stream) {
    (void)in_sizes; (void)n_in; (void)out_size; (void)ws_size;
    const float* x_in = (const float*)d_in[0];
    const float* h0   = (const float*)d_in[1];
    const float* c0   = (const float*)d_in[2];
    const int*   mk   = (const int*)d_in[3];
    const float* Wemb = (const float*)d_in[4];
    const float* bemb = (const float*)d_in[5];
    const float* Wih  = (const float*)d_in[6];
    const float* bih  = (const float*)d_in[7];
    const float* Whh  = (const float*)d_in[8];
    const float* bhh  = (const float*)d_in[9];
    const float* Wout = (const float*)d_in[10];
    const float* bout = (const float*)d_in[11];

    unsigned short* wcat = (unsigned short*)d_ws;        // 49152 uint4 = 768 KB
    unsigned short* wouf = wcat + 393216;                // 512 uint4 = 8 KB
    float*          bsg  = (float*)(wouf + 4096);        // 1024 f32

    prep_wcat<<<192, 256, 0, stream>>>(Whh, Wih, wcat);
    prep_wout<<<2, 256, 0, stream>>>(Wout, wouf);
    prep_bias<<<4, 256, 0, stream>>>(bih, bhh, bsg);

    float* outp = (float*)d_out;
    lstm_main<<<1024, 1024, 0, stream>>>(x_in, h0, c0, mk, Wemb, bemb, bout,
                                         wcat, wouf, bsg, outp);
}

// Round 14
// 2262.381 us; speedup vs baseline: 1.6314x; 1.5922x over previous
//
#include <hip/hip_runtime.h>

#define T_STEPS 19
#define NBATCH  65536
#define RNN     256
#define EMB     128
#define KDIM    384   // RNN + EMB
#define ROWB    768   // KDIM * 2 bytes (LDS row stride)
#define SWZ(row) (((row) & 15) << 4)

typedef __bf16 bf16x8 __attribute__((ext_vector_type(8)));
typedef float  f32x4  __attribute__((ext_vector_type(4)));

#define BLOCK_SYNC() asm volatile("s_waitcnt lgkmcnt(0)\n\ts_barrier" ::: "memory")

__device__ __forceinline__ unsigned short f2bf(float f) {
    unsigned u = __float_as_uint(f);
    u += 0x7fffu + ((u >> 16) & 1u);
    return (unsigned short)(u >> 16);
}
__device__ __forceinline__ float bf2f(unsigned short u) {
    return __uint_as_float(((unsigned)u) << 16);
}
__device__ __forceinline__ float sigm_(float x) {
    float e = __expf(-x);
    return __builtin_amdgcn_rcpf(1.0f + e);
}
__device__ __forceinline__ float tanh_(float x) {
    float e = __expf(2.0f * x);
    return 1.0f - 2.0f * __builtin_amdgcn_rcpf(e + 1.0f);
}

// ---- prep: Wcat fragments for 16x16x32 MFMA, wave-private slices (r7 layout) ----
// uint4 idx = ((w*12 + kk)*4 + g)*64 + l
//   j = g*256 + w*16 + (l&15) ; k = kk*32 + (l>>4)*8 + e
__global__ void prep_wcat(const float* __restrict__ Whh, const float* __restrict__ Wih,
                          unsigned short* __restrict__ dst) {
    int tid = blockIdx.x * 256 + threadIdx.x;   // 49152 total
    int l   = tid & 63;
    int p   = tid >> 6;
    int g   = p & 3;
    int kkw = p >> 2;
    int kk  = kkw % 12;
    int w   = kkw / 12;
    int j   = g * 256 + w * 16 + (l & 15);
    int kb  = kk * 32 + (l >> 4) * 8;
    unsigned short v[8];
#pragma unroll
    for (int e = 0; e < 8; ++e) {
        int k = kb + e;
        float f = (k < 256) ? Whh[j * 256 + k] : Wih[j * 128 + (k - 256)];
        v[e] = f2bf(f);
    }
    uint4 pk;
    pk.x = (unsigned)v[0] | ((unsigned)v[1] << 16);
    pk.y = (unsigned)v[2] | ((unsigned)v[3] << 16);
    pk.z = (unsigned)v[4] | ((unsigned)v[5] << 16);
    pk.w = (unsigned)v[6] | ((unsigned)v[7] << 16);
    ((uint4*)dst)[tid] = pk;
}

// ---- prep: Wout fragments for 16x16x32 (16-col tile, cols 5..15 zero) ----
__global__ void prep_wout(const float* __restrict__ Wout, unsigned short* __restrict__ dst) {
    int tid = blockIdx.x * 256 + threadIdx.x;   // 512 total
    if (tid >= 512) return;
    int l  = tid & 63;
    int kk = tid >> 6;
    int q  = l & 15;
    int kb = kk * 32 + (l >> 4) * 8;
    unsigned short v[8];
#pragma unroll
    for (int e = 0; e < 8; ++e) {
        float f = (q < 5) ? Wout[q * 256 + kb + e] : 0.0f;
        v[e] = f2bf(f);
    }
    uint4 pk;
    pk.x = (unsigned)v[0] | ((unsigned)v[1] << 16);
    pk.y = (unsigned)v[2] | ((unsigned)v[3] << 16);
    pk.z = (unsigned)v[4] | ((unsigned)v[5] << 16);
    pk.w = (unsigned)v[6] | ((unsigned)v[7] << 16);
    ((uint4*)dst)[tid] = pk;
}

__global__ void prep_bias(const float* __restrict__ bih, const float* __restrict__ bhh,
                          float* __restrict__ dst) {
    int tid = blockIdx.x * 256 + threadIdx.x;
    if (tid < 1024) dst[tid] = bih[tid] + bhh[tid];
}

// ---- main persistent-over-T kernel: 1 block = 64 samples, 16 waves, 4 waves/SIMD ----
// EXACT round-7 schedule/addressing; only additions: x/mask register prefetch,
// W_emb/b_emb cached in LDS, ballot mask.
__global__ __launch_bounds__(1024, 4)
void lstm_main(const float* __restrict__ x_in, const float* __restrict__ h_in,
               const float* __restrict__ c_in, const int* __restrict__ mask,
               const float* __restrict__ W_emb, const float* __restrict__ b_emb,
               const float* __restrict__ b_out,
               const unsigned short* __restrict__ wcat_fr,
               const unsigned short* __restrict__ wout_fr,
               const float* __restrict__ bias_g,
               float* __restrict__ out) {
    __shared__ unsigned short A_lds[64 * KDIM];   // 48 KB, XOR-swizzled (r7)
    __shared__ float c_lds[64 * RNN];             // 64 KB fp32 c state
    __shared__ float we_lds[384];                 // W_emb(256) + b_emb(128)

    const int tid  = threadIdx.x;
    const int lane = tid & 63;
    const int w    = tid >> 6;         // wave 0..15 = unit-block
    const int base = blockIdx.x * 64;
    const int csub = lane & 15;
    const int kq   = lane >> 4;        // 0..3
    const int unit = w * 16 + csub;

    // init: h0 -> A_lds (bf16), c0 -> c_lds (fp32)
#pragma unroll
    for (int m = 0; m < 4; ++m)
#pragma unroll
        for (int r = 0; r < 4; ++r) {
            int row = m * 16 + kq * 4 + r;
            float hv = h_in[(size_t)(base + row) * RNN + unit];
            c_lds[row * RNN + unit] = c_in[(size_t)(base + row) * RNN + unit];
            int byte = (row * ROWB + unit * 2) ^ SWZ(row);
            A_lds[byte >> 1] = f2bf(hv);
        }
    if (tid < 384) we_lds[tid] = (tid < 256) ? W_emb[tid] : b_emb[tid - 256];

    float bias4[4];
#pragma unroll
    for (int g = 0; g < 4; ++g) bias4[g] = bias_g[g * 256 + unit];
    const float bo = (csub < 5) ? b_out[csub] : 0.0f;

    const uint4* wfp = (const uint4*)wcat_fr + (size_t)w * (12 * 4 * 64) + lane;
    const uint4* wop = (const uint4*)wout_fr + lane;

    // persistent depth-2 weight pipeline (regs), wraps across steps (r7)
    bf16x8 bA[4], bB[4];
#pragma unroll
    for (int g = 0; g < 4; ++g) bA[g] = *(const bf16x8*)(wfp + (0 * 4 + g) * 64);
#pragma unroll
    for (int g = 0; g < 4; ++g) bB[g] = *(const bf16x8*)(wfp + (1 * 4 + g) * 64);

    // x/mask prefetch for t=0
    const int xrow = tid >> 4, xjc = (tid & 15) * 8;
    float xc0, xc1;
    {
        const float* xp = x_in + ((size_t)base + xrow) * 2;
        xc0 = xp[0]; xc1 = xp[1];
    }
    int mvc = mask[base + lane];

    BLOCK_SYNC();  // init LDS (h, c, we_lds) visible

    for (int t = 0; t < T_STEPS; ++t) {
        unsigned long long mbits = __ballot(mvc != 0);

        // ---- Phase A: e(t) = relu(x @ W_emb + b_emb) from prefetched x ----
        {
            unsigned pk[4];
#pragma unroll
            for (int e = 0; e < 8; e += 2) {
                int j = xjc + e;
                float e0 = fmaxf(fmaf(xc0, we_lds[j],     fmaf(xc1, we_lds[128 + j],     we_lds[256 + j])),     0.0f);
                float e1 = fmaxf(fmaf(xc0, we_lds[j + 1], fmaf(xc1, we_lds[128 + j + 1], we_lds[256 + j + 1])), 0.0f);
                pk[e >> 1] = (unsigned)f2bf(e0) | ((unsigned)f2bf(e1) << 16);
            }
            int byte = (xrow * ROWB + 512 + 2 * xjc) ^ SWZ(xrow);
            *(uint4*)((char*)A_lds + byte) = make_uint4(pk[0], pk[1], pk[2], pk[3]);
        }
        // prefetch x/mask for t+1 (lands during B+C)
        {
            int tn = (t + 1 < T_STEPS) ? t + 1 : t;
            const float* xp = x_in + ((size_t)tn * NBATCH + base + xrow) * 2;
            xc0 = xp[0]; xc1 = xp[1];
            mvc = mask[(size_t)tn * NBATCH + base + lane];
        }
        BLOCK_SYNC();  // bar1: A_lds ready

        // ---- Phase B: r7-verbatim — runtime kk loop, depth-2 reg pipeline ----
        f32x4 acc[4][4];
#pragma unroll
        for (int m = 0; m < 4; ++m)
#pragma unroll
            for (int g = 0; g < 4; ++g) {
                f32x4 z = {bias4[g], bias4[g], bias4[g], bias4[g]};
                acc[m][g] = z;
            }
#pragma unroll 1
        for (int kp = 0; kp < 6; ++kp) {
            int kk0 = kp * 2;
            {
#pragma unroll
                for (int m = 0; m < 4; ++m) {
                    int row = m * 16 + csub;
                    int byte = row * ROWB + kk0 * 64 + kq * 16;
                    byte ^= SWZ(row);
                    bf16x8 a = *(const bf16x8*)((const char*)A_lds + byte);
                    acc[m][0] = __builtin_amdgcn_mfma_f32_16x16x32_bf16(a, bA[0], acc[m][0], 0, 0, 0);
                    acc[m][1] = __builtin_amdgcn_mfma_f32_16x16x32_bf16(a, bA[1], acc[m][1], 0, 0, 0);
                    acc[m][2] = __builtin_amdgcn_mfma_f32_16x16x32_bf16(a, bA[2], acc[m][2], 0, 0, 0);
                    acc[m][3] = __builtin_amdgcn_mfma_f32_16x16x32_bf16(a, bA[3], acc[m][3], 0, 0, 0);
                }
                int kn = kk0 + 2; if (kn >= 12) kn -= 12;   // wraps to next step (same weights)
#pragma unroll
                for (int g = 0; g < 4; ++g)
                    bA[g] = *(const bf16x8*)(wfp + (kn * 4 + g) * 64);
            }
            {
                int kk1 = kk0 + 1;
#pragma unroll
                for (int m = 0; m < 4; ++m) {
                    int row = m * 16 + csub;
                    int byte = row * ROWB + kk1 * 64 + kq * 16;
                    byte ^= SWZ(row);
                    bf16x8 a = *(const bf16x8*)((const char*)A_lds + byte);
                    acc[m][0] = __builtin_amdgcn_mfma_f32_16x16x32_bf16(a, bB[0], acc[m][0], 0, 0, 0);
                    acc[m][1] = __builtin_amdgcn_mfma_f32_16x16x32_bf16(a, bB[1], acc[m][1], 0, 0, 0);
                    acc[m][2] = __builtin_amdgcn_mfma_f32_16x16x32_bf16(a, bB[2], acc[m][2], 0, 0, 0);
                    acc[m][3] = __builtin_amdgcn_mfma_f32_16x16x32_bf16(a, bB[3], acc[m][3], 0, 0, 0);
                }
                int kn = kk1 + 2; if (kn >= 12) kn -= 12;
#pragma unroll
                for (int g = 0; g < 4; ++g)
                    bB[g] = *(const bf16x8*)(wfp + (kn * 4 + g) * 64);
            }
        }
        BLOCK_SYNC();  // bar2: all A_lds reads done before h overwrite

        // ---- Phase C: elementwise update; c in LDS, h (bf16) back to A_lds ----
#pragma unroll
        for (int m = 0; m < 4; ++m)
#pragma unroll
            for (int r = 0; r < 4; ++r) {
                int row = m * 16 + kq * 4 + r;
                float cv = c_lds[row * RNN + unit];
                float iv = sigm_(acc[m][0][r]);
                float fv = sigm_(acc[m][1][r]);
                float gv = tanh_(acc[m][2][r]);
                float ov = sigm_(acc[m][3][r]);
                float cn = fmaf(fv, cv, iv * gv);
                float hn = ov * tanh_(cn);
                int msk = (int)((mbits >> row) & 1ull);
                if (msk) {
                    c_lds[row * RNN + unit] = cn;
                    int byte = (row * ROWB + unit * 2) ^ SWZ(row);
                    A_lds[byte >> 1] = f2bf(hn);
                }
            }
        BLOCK_SYNC();  // bar3: new h visible

        // ---- Phase D: out = h @ Wout^T + b_out (waves 0..3), overlaps next Phase A ----
        if (w < 4) {
            f32x4 oacc = {bo, bo, bo, bo};
#pragma unroll
            for (int kk = 0; kk < 8; ++kk) {
                int row = w * 16 + csub;
                int byte = row * ROWB + kk * 64 + kq * 16;
                byte ^= SWZ(row);
                bf16x8 a  = *(const bf16x8*)((const char*)A_lds + byte);
                bf16x8 bw = *(const bf16x8*)(wop + kk * 64);
                oacc = __builtin_amdgcn_mfma_f32_16x16x32_bf16(a, bw, oacc, 0, 0, 0);
            }
            if (csub < 5) {
#pragma unroll
                for (int r = 0; r < 4; ++r) {
                    int row = w * 16 + kq * 4 + r;
                    int msk = (int)((mbits >> row) & 1ull);
                    out[((size_t)t * NBATCH + base + row) * 5 + csub] = msk ? oacc[r] : 0.0f;
                }
            }
        }
        // no barrier: D reads h-region (k<256); next A writes e-region (k>=256) — disjoint.
        // C(t+1) writes are behind bar1+bar2.
    }

    // ---- final states: h from A_lds (bf16), c from c_lds (fp32) ----
    float* hout = out + (size_t)T_STEPS * NBATCH * 5;
    float* cout = hout + (size_t)NBATCH * RNN;
#pragma unroll
    for (int m = 0; m < 4; ++m)
#pragma unroll
        for (int r = 0; r < 4; ++r) {
            int row = m * 16 + kq * 4 + r;
            int byte = (row * ROWB + unit * 2) ^ SWZ(row);
            hout[(size_t)(base + row) * RNN + unit] = bf2f(A_lds[byte >> 1]);
            cout[(size_t)(base + row) * RNN + unit] = c_lds[row * RNN + unit];
        }
}

extern "C" void kernel_launch(void* const* d_in, const int* in_sizes, int n_in,
                              void* d_out, int out_size, void* d_ws, size_t ws_size,
                              hipStream_t stream) {
    (void)in_sizes; (void)n_in; (void)out_size; (void)ws_size;
    const float* x_in = (const float*)d_in[0];
    const float* h0   = (const float*)d_in[1];
    const float* c0   = (const float*)d_in[2];
    const int*   mk   = (const int*)d_in[3];
    const float* Wemb = (const float*)d_in[4];
    const float* bemb = (const float*)d_in[5];
    const float* Wih  = (const float*)d_in[6];
    const float* bih  = (const float*)d_in[7];
    const float* Whh  = (const float*)d_in[8];
    const float* bhh  = (const float*)d_in[9];
    const float* Wout = (const float*)d_in[10];
    const float* bout = (const float*)d_in[11];

    unsigned short* wcat = (unsigned short*)d_ws;        // 49152 uint4 = 768 KB
    unsigned short* wouf = wcat + 393216;                // 512 uint4 = 8 KB
    float*          bsg  = (float*)(wouf + 4096);        // 1024 f32

    prep_wcat<<<192, 256, 0, stream>>>(Whh, Wih, wcat);
    prep_wout<<<2, 256, 0, stream>>>(Wout, wouf);
    prep_bias<<<4, 256, 0, stream>>>(bih, bhh, bsg);

    float* outp = (float*)d_out;
    lstm_main<<<1024, 1024, 0, stream>>>(x_in, h0, c0, mk, Wemb, bemb, bout,
                                         wcat, wouf, bsg, outp);
}

// Round 15
// 2107.820 us; speedup vs baseline: 1.7511x; 1.0733x over previous
//
#include <hip/hip_runtime.h>

#define T_STEPS 19
#define NBATCH  65536
#define RNN     256
#define EMB     128
#define KDIM    384   // RNN + EMB
#define ROWS    32    // samples per block (2 blocks/CU)
#define ROWB    768   // KDIM * 2 bytes (LDS row stride)
#define SWZ(row) (((row) & 15) << 4)

typedef __bf16 bf16x8 __attribute__((ext_vector_type(8)));
typedef float  f32x4  __attribute__((ext_vector_type(4)));

#define BLOCK_SYNC() asm volatile("s_waitcnt lgkmcnt(0)\n\ts_barrier" ::: "memory")

__device__ __forceinline__ unsigned short f2bf(float f) {
    unsigned u = __float_as_uint(f);
    u += 0x7fffu + ((u >> 16) & 1u);
    return (unsigned short)(u >> 16);
}
__device__ __forceinline__ float bf2f(unsigned short u) {
    return __uint_as_float(((unsigned)u) << 16);
}
__device__ __forceinline__ float sigm_(float x) {
    float e = __expf(-x);
    return __builtin_amdgcn_rcpf(1.0f + e);
}
__device__ __forceinline__ float tanh_(float x) {
    float e = __expf(2.0f * x);
    return 1.0f - 2.0f * __builtin_amdgcn_rcpf(e + 1.0f);
}

// ---- prep: Wcat fragments; wave w (of 8) owns units [w*32, w*32+32), all 4 gates ----
// uint4 idx = ((w*12 + kk)*8 + usub*4 + g)*64 + l
//   j = g*256 + w*32 + usub*16 + (l&15) ; k = kk*32 + (l>>4)*8 + e
__global__ void prep_wcat(const float* __restrict__ Whh, const float* __restrict__ Wih,
                          unsigned short* __restrict__ dst) {
    int tid = blockIdx.x * 256 + threadIdx.x;   // 49152 total
    int l    = tid & 63;
    int p    = tid >> 6;         // 0..767
    int g    = p & 3;
    int usub = (p >> 2) & 1;
    int kkw  = p >> 3;           // w*12 + kk
    int kk   = kkw % 12;
    int w    = kkw / 12;         // 0..7
    int j    = g * 256 + w * 32 + usub * 16 + (l & 15);
    int kb   = kk * 32 + (l >> 4) * 8;
    unsigned short v[8];
#pragma unroll
    for (int e = 0; e < 8; ++e) {
        int k = kb + e;
        float f = (k < 256) ? Whh[j * 256 + k] : Wih[j * 128 + (k - 256)];
        v[e] = f2bf(f);
    }
    uint4 pk;
    pk.x = (unsigned)v[0] | ((unsigned)v[1] << 16);
    pk.y = (unsigned)v[2] | ((unsigned)v[3] << 16);
    pk.z = (unsigned)v[4] | ((unsigned)v[5] << 16);
    pk.w = (unsigned)v[6] | ((unsigned)v[7] << 16);
    ((uint4*)dst)[tid] = pk;
}

// ---- prep: Wout fragments for 16x16x32 (16-col tile, cols 5..15 zero) ----
__global__ void prep_wout(const float* __restrict__ Wout, unsigned short* __restrict__ dst) {
    int tid = blockIdx.x * 256 + threadIdx.x;   // 512 total
    if (tid >= 512) return;
    int l  = tid & 63;
    int kk = tid >> 6;
    int q  = l & 15;
    int kb = kk * 32 + (l >> 4) * 8;
    unsigned short v[8];
#pragma unroll
    for (int e = 0; e < 8; ++e) {
        float f = (q < 5) ? Wout[q * 256 + kb + e] : 0.0f;
        v[e] = f2bf(f);
    }
    uint4 pk;
    pk.x = (unsigned)v[0] | ((unsigned)v[1] << 16);
    pk.y = (unsigned)v[2] | ((unsigned)v[3] << 16);
    pk.z = (unsigned)v[4] | ((unsigned)v[5] << 16);
    pk.w = (unsigned)v[6] | ((unsigned)v[7] << 16);
    ((uint4*)dst)[tid] = pk;
}

__global__ void prep_bias(const float* __restrict__ bih, const float* __restrict__ bhh,
                          float* __restrict__ dst) {
    int tid = blockIdx.x * 256 + threadIdx.x;
    if (tid < 1024) dst[tid] = bih[tid] + bhh[tid];
}

// ---- main: 1 block = 32 samples, 8 waves, 2 blocks/CU (two barrier domains) ----
// Per-block schedule is r7-verbatim. Wave tile: 32 rows x 32 units x 4 gates,
// acc[2][2][4]=64 regs; weight pipe: 24 half-slices, depth-2 (32 regs).
__global__ __launch_bounds__(512, 4)
void lstm_main(const float* __restrict__ x_in, const float* __restrict__ h_in,
               const float* __restrict__ c_in, const int* __restrict__ mask,
               const float* __restrict__ W_emb, const float* __restrict__ b_emb,
               const float* __restrict__ b_out,
               const unsigned short* __restrict__ wcat_fr,
               const unsigned short* __restrict__ wout_fr,
               const float* __restrict__ bias_g,
               float* __restrict__ out) {
    __shared__ unsigned short A_lds[ROWS * KDIM];  // 24 KB, XOR-swizzled (r7)
    __shared__ float c_lds[ROWS * RNN];            // 32 KB fp32 c state
    __shared__ float b_lds[1024];                  // 4 KB gate bias
    __shared__ int   m_lds[2][ROWS];

    const int tid  = threadIdx.x;
    const int lane = tid & 63;
    const int w    = tid >> 6;         // wave 0..7 = unit-block (32 units)
    const int base = blockIdx.x * ROWS;
    const int csub = lane & 15;
    const int kq   = lane >> 4;        // 0..3

    // init: h0 -> A_lds (bf16), c0 -> c_lds (fp32); bias -> LDS
#pragma unroll
    for (int m = 0; m < 2; ++m)
#pragma unroll
        for (int usub = 0; usub < 2; ++usub)
#pragma unroll
            for (int r = 0; r < 4; ++r) {
                int row  = m * 16 + kq * 4 + r;
                int unit = w * 32 + usub * 16 + csub;
                float hv = h_in[(size_t)(base + row) * RNN + unit];
                c_lds[row * RNN + unit] = c_in[(size_t)(base + row) * RNN + unit];
                int byte = (row * ROWB + unit * 2) ^ SWZ(row);
                A_lds[byte >> 1] = f2bf(hv);
            }
    b_lds[tid]       = bias_g[tid];
    b_lds[tid + 512] = bias_g[tid + 512];
    const float bo = (csub < 5) ? b_out[csub] : 0.0f;

    const uint4* wfp = (const uint4*)wcat_fr + (size_t)w * (12 * 8 * 64) + lane;
    const uint4* wop = (const uint4*)wout_fr + lane;

    // persistent depth-2 weight pipeline over 24 half-slices (hh = kk*2 + usub)
    bf16x8 bA[4], bB[4];
#pragma unroll
    for (int g = 0; g < 4; ++g) bA[g] = *(const bf16x8*)(wfp + (0 * 4 + g) * 64);
#pragma unroll
    for (int g = 0; g < 4; ++g) bB[g] = *(const bf16x8*)(wfp + (1 * 4 + g) * 64);

    BLOCK_SYNC();  // init LDS visible

    for (int t = 0; t < T_STEPS; ++t) {
        // ---- Phase A: e = relu(x @ W_emb + b_emb) -> A_lds k=256..383; mask -> LDS ----
        {
            int row = tid >> 4;            // 0..31
            int jc  = (tid & 15) * 8;
            const float* xp = x_in + ((size_t)t * NBATCH + base + row) * 2;
            float x0 = xp[0], x1 = xp[1];
            unsigned pk[4];
#pragma unroll
            for (int e = 0; e < 8; e += 2) {
                int j = jc + e;
                float e0 = fmaxf(fmaf(x0, W_emb[j],     fmaf(x1, W_emb[128 + j],     b_emb[j])),     0.0f);
                float e1 = fmaxf(fmaf(x0, W_emb[j + 1], fmaf(x1, W_emb[128 + j + 1], b_emb[j + 1])), 0.0f);
                pk[e >> 1] = (unsigned)f2bf(e0) | ((unsigned)f2bf(e1) << 16);
            }
            int byte = (row * ROWB + 512 + 2 * jc) ^ SWZ(row);
            *(uint4*)((char*)A_lds + byte) = make_uint4(pk[0], pk[1], pk[2], pk[3]);
            if (tid < ROWS) m_lds[t & 1][tid] = mask[(size_t)t * NBATCH + base + tid];
        }
        BLOCK_SYNC();  // bar1: A_lds + mask ready

        // ---- Phase B: gates 32 rows x 32 units x 4 gates; 12 kk, 2 halves each ----
        f32x4 acc[2][2][4];   // [m][usub][g]
#pragma unroll
        for (int m = 0; m < 2; ++m)
#pragma unroll
            for (int usub = 0; usub < 2; ++usub)
#pragma unroll
                for (int g = 0; g < 4; ++g) {
                    float b = b_lds[g * 256 + w * 32 + usub * 16 + csub];
                    f32x4 z = {b, b, b, b};
                    acc[m][usub][g] = z;
                }
#pragma unroll 1
        for (int hp = 0; hp < 12; ++hp) {
            // a-frags for kk=hp (shared by both halves)
            int b0 = (csub * ROWB + hp * 64 + kq * 16) ^ SWZ(csub);
            bf16x8 a0 = *(const bf16x8*)((const char*)A_lds + b0);
            int row1 = 16 + csub;
            int b1 = (row1 * ROWB + hp * 64 + kq * 16) ^ SWZ(row1);
            bf16x8 a1 = *(const bf16x8*)((const char*)A_lds + b1);
            {   // even half (usub=0): consume bA, refill hh+2
                acc[0][0][0] = __builtin_amdgcn_mfma_f32_16x16x32_bf16(a0, bA[0], acc[0][0][0], 0, 0, 0);
                acc[1][0][0] = __builtin_amdgcn_mfma_f32_16x16x32_bf16(a1, bA[0], acc[1][0][0], 0, 0, 0);
                acc[0][0][1] = __builtin_amdgcn_mfma_f32_16x16x32_bf16(a0, bA[1], acc[0][0][1], 0, 0, 0);
                acc[1][0][1] = __builtin_amdgcn_mfma_f32_16x16x32_bf16(a1, bA[1], acc[1][0][1], 0, 0, 0);
                acc[0][0][2] = __builtin_amdgcn_mfma_f32_16x16x32_bf16(a0, bA[2], acc[0][0][2], 0, 0, 0);
                acc[1][0][2] = __builtin_amdgcn_mfma_f32_16x16x32_bf16(a1, bA[2], acc[1][0][2], 0, 0, 0);
                acc[0][0][3] = __builtin_amdgcn_mfma_f32_16x16x32_bf16(a0, bA[3], acc[0][0][3], 0, 0, 0);
                acc[1][0][3] = __builtin_amdgcn_mfma_f32_16x16x32_bf16(a1, bA[3], acc[1][0][3], 0, 0, 0);
                int hn = 2 * hp + 2; if (hn >= 24) hn -= 24;  // wraps to next step (same weights)
#pragma unroll
                for (int g = 0; g < 4; ++g)
                    bA[g] = *(const bf16x8*)(wfp + (hn * 4 + g) * 64);
            }
            {   // odd half (usub=1): consume bB, refill hh+2
                acc[0][1][0] = __builtin_amdgcn_mfma_f32_16x16x32_bf16(a0, bB[0], acc[0][1][0], 0, 0, 0);
                acc[1][1][0] = __builtin_amdgcn_mfma_f32_16x16x32_bf16(a1, bB[0], acc[1][1][0], 0, 0, 0);
                acc[0][1][1] = __builtin_amdgcn_mfma_f32_16x16x32_bf16(a0, bB[1], acc[0][1][1], 0, 0, 0);
                acc[1][1][1] = __builtin_amdgcn_mfma_f32_16x16x32_bf16(a1, bB[1], acc[1][1][1], 0, 0, 0);
                acc[0][1][2] = __builtin_amdgcn_mfma_f32_16x16x32_bf16(a0, bB[2], acc[0][1][2], 0, 0, 0);
                acc[1][1][2] = __builtin_amdgcn_mfma_f32_16x16x32_bf16(a1, bB[2], acc[1][1][2], 0, 0, 0);
                acc[0][1][3] = __builtin_amdgcn_mfma_f32_16x16x32_bf16(a0, bB[3], acc[0][1][3], 0, 0, 0);
                acc[1][1][3] = __builtin_amdgcn_mfma_f32_16x16x32_bf16(a1, bB[3], acc[1][1][3], 0, 0, 0);
                int hn = 2 * hp + 3; if (hn >= 24) hn -= 24;
#pragma unroll
                for (int g = 0; g < 4; ++g)
                    bB[g] = *(const bf16x8*)(wfp + (hn * 4 + g) * 64);
            }
        }
        BLOCK_SYNC();  // bar2: all A_lds reads done before h overwrite

        // ---- Phase C: elementwise update; c in LDS, h (bf16) back to A_lds ----
#pragma unroll
        for (int m = 0; m < 2; ++m)
#pragma unroll
            for (int usub = 0; usub < 2; ++usub)
#pragma unroll
                for (int r = 0; r < 4; ++r) {
                    int row  = m * 16 + kq * 4 + r;
                    int unit = w * 32 + usub * 16 + csub;
                    float cv = c_lds[row * RNN + unit];
                    float iv = sigm_(acc[m][usub][0][r]);
                    float fv = sigm_(acc[m][usub][1][r]);
                    float gv = tanh_(acc[m][usub][2][r]);
                    float ov = sigm_(acc[m][usub][3][r]);
                    float cn = fmaf(fv, cv, iv * gv);
                    float hn = ov * tanh_(cn);
                    if (m_lds[t & 1][row]) {
                        c_lds[row * RNN + unit] = cn;
                        int byte = (row * ROWB + unit * 2) ^ SWZ(row);
                        A_lds[byte >> 1] = f2bf(hn);
                    }
                }
        BLOCK_SYNC();  // bar3: new h visible

        // ---- Phase D: out = h @ Wout^T + b_out (waves 0,1), overlaps next Phase A ----
        if (w < 2) {
            f32x4 oacc = {bo, bo, bo, bo};
#pragma unroll
            for (int kk = 0; kk < 8; ++kk) {
                int row = w * 16 + csub;
                int byte = (row * ROWB + kk * 64 + kq * 16) ^ SWZ(row);
                bf16x8 a  = *(const bf16x8*)((const char*)A_lds + byte);
                bf16x8 bw = *(const bf16x8*)(wop + kk * 64);
                oacc = __builtin_amdgcn_mfma_f32_16x16x32_bf16(a, bw, oacc, 0, 0, 0);
            }
            if (csub < 5) {
#pragma unroll
                for (int r = 0; r < 4; ++r) {
                    int row = w * 16 + kq * 4 + r;
                    int msk = m_lds[t & 1][row];
                    out[((size_t)t * NBATCH + base + row) * 5 + csub] = msk ? oacc[r] : 0.0f;
                }
            }
        }
        // no barrier: D reads h-region (k<256) + m_lds[t&1]; next A writes e-region
        // (k>=256) + m_lds[(t+1)&1] — disjoint. C(t+1) writes are behind bar1+bar2.
    }

    // ---- final states: h from A_lds (bf16), c from c_lds (fp32) ----
    float* hout = out + (size_t)T_STEPS * NBATCH * 5;
    float* cout = hout + (size_t)NBATCH * RNN;
#pragma unroll
    for (int m = 0; m < 2; ++m)
#pragma unroll
        for (int usub = 0; usub < 2; ++usub)
#pragma unroll
            for (int r = 0; r < 4; ++r) {
                int row  = m * 16 + kq * 4 + r;
                int unit = w * 32 + usub * 16 + csub;
                int byte = (row * ROWB + unit * 2) ^ SWZ(row);
                hout[(size_t)(base + row) * RNN + unit] = bf2f(A_lds[byte >> 1]);
                cout[(size_t)(base + row) * RNN + unit] = c_lds[row * RNN + unit];
            }
}

extern "C" void kernel_launch(void* const* d_in, const int* in_sizes, int n_in,
                              void* d_out, int out_size, void* d_ws, size_t ws_size,
                              hipStream_t stream) {
    (void)in_sizes; (void)n_in; (void)out_size; (void)ws_size;
    const float* x_in = (const float*)d_in[0];
    const float* h0   = (const float*)d_in[1];
    const float* c0   = (const float*)d_in[2];
    const int*   mk   = (const int*)d_in[3];
    const float* Wemb = (const float*)d_in[4];
    const float* bemb = (const float*)d_in[5];
    const float* Wih  = (const float*)d_in[6];
    const float* bih  = (const float*)d_in[7];
    const float* Whh  = (const float*)d_in[8];
    const float* bhh  = (const float*)d_in[9];
    const float* Wout = (const float*)d_in[10];
    const float* bout = (const float*)d_in[11];

    unsigned short* wcat = (unsigned short*)d_ws;        // 49152 uint4 = 768 KB
    unsigned short* wouf = wcat + 393216;                // 512 uint4 = 8 KB
    float*          bsg  = (float*)(wouf + 4096);        // 1024 f32

    prep_wcat<<<192, 256, 0, stream>>>(Whh, Wih, wcat);
    prep_wout<<<2, 256, 0, stream>>>(Wout, wouf);
    prep_bias<<<4, 256, 0, stream>>>(bih, bhh, bsg);

    float* outp = (float*)d_out;
    lstm_main<<<2048, 512, 0, stream>>>(x_in, h0, c0, mk, Wemb, bemb, bout,
                                        wcat, wouf, bsg, outp);
}